// Round 5
// baseline (721.454 us; speedup 1.0000x reference)
//
#include <hip/hip_runtime.h>

// Levelized STA, persistent-kernel version.
// One cooperative kernel; 32 grid barriers replace 31 kernel boundaries
// (each boundary cost ~14us in R4: launch + cross-XCD L2 flush/inv).
//
// d_out (floats): [0,LP) arrival | [LP,2LP) required | [2LP,3LP) slack
//                 | [3LP,3LP+NNETS) mask as 0.0/1.0
// d_ws (ints): [0,NBITW) net-ignore bitmask | [32768] barrier cnt | [32800] flag
//
// XCD-coherence discipline (L2s not cross-coherent; no flushes inside kernel):
//   - cross-block-visible writes (arr levels, req init, bits): agent-scope stores
//   - reads of atomic-updated req: agent-scope loads (bypass stale local lines)
//   - arr gathers / bits reads: NORMAL cached loads — safe because each datum
//     is written before any XCD first reads it (no pre-write copy can exist),
//     and beneficial (gather region becomes L2-resident).
constexpr int L = 32;
constexpr int P = 131072;        // 2^17
constexpr int LP = L * P;
constexpr int NNETS = 1000000;
constexpr int NBITW = NNETS / 32;  // 31250 (exact)
constexpr int NBLK = 512;
constexpr int TPB = 256;         // NBLK*TPB == P exactly
constexpr float TPER = 10.0f;
constexpr float NEGV = -1e30f;
constexpr int WS_CNT = 32768;    // int index into ws
constexpr int WS_FLAG = WS_CNT + 32;  // separate cache line from cnt

__device__ __forceinline__ float agent_load_f(const float* p) {
  return __hip_atomic_load(p, __ATOMIC_RELAXED, __HIP_MEMORY_SCOPE_AGENT);
}
__device__ __forceinline__ void agent_store_f(float* p, float v) {
  __hip_atomic_store(p, v, __ATOMIC_RELAXED, __HIP_MEMORY_SCOPE_AGENT);
}
__device__ __forceinline__ void agent_store_i(int* p, int v) {
  __hip_atomic_store(p, v, __ATOMIC_RELAXED, __HIP_MEMORY_SCOPE_AGENT);
}

// Float atomic-min via int-min (>=0) / uint-max (<0); correct for all sign mixes.
__device__ __forceinline__ void atomic_min_f32(float* addr, float val) {
  if (val >= 0.0f) {
    atomicMin(reinterpret_cast<int*>(addr), __float_as_int(val));
  } else {
    atomicMax(reinterpret_cast<unsigned int*>(addr), __float_as_uint(val));
  }
}

// Grid barrier: monotonic epoch, no counter reset (no reset race).
// Every wave drains its own vmem (incl. non-returning atomics) before the
// block barrier; one arrival atomic per block.
__device__ __forceinline__ void gbar(int* cnt, int* flag, int epoch) {
  asm volatile("s_waitcnt vmcnt(0)" ::: "memory");
  __syncthreads();
  if (threadIdx.x == 0) {
    int old = __hip_atomic_fetch_add(cnt, 1, __ATOMIC_RELAXED,
                                     __HIP_MEMORY_SCOPE_AGENT);
    if (old == epoch * NBLK - 1) {
      __hip_atomic_store(flag, epoch, __ATOMIC_RELAXED,
                         __HIP_MEMORY_SCOPE_AGENT);
    } else {
      while (__hip_atomic_load(flag, __ATOMIC_RELAXED,
                               __HIP_MEMORY_SCOPE_AGENT) < epoch) {
        __builtin_amdgcn_s_sleep(2);
      }
    }
  }
  __syncthreads();
}

__global__ __launch_bounds__(TPB) void sta_persist(
    const float* __restrict__ delays, const int* __restrict__ src,
    const int* __restrict__ net, const int* __restrict__ mask,
    float* __restrict__ out, int* __restrict__ ws) {
  const int p = blockIdx.x * TPB + threadIdx.x;  // [0,P): this thread's pin
  float* arr = out;
  float* req = out + LP;
  float* slk = out + 2 * LP;
  float* mf = out + 3 * LP;
  int* bits = ws;
  int* cnt = ws + WS_CNT;
  int* flag = ws + WS_FLAG;

  // ---- prologue: bits, req=TPER (all levels), arr[0]=delays[0], mask->float
  if (p < NBITW) {
    const int* mp = mask + p * 32;
    unsigned w = 0;
#pragma unroll
    for (int j = 0; j < 32; ++j) w |= (mp[j] ? 1u : 0u) << j;
    agent_store_i(bits + p, (int)w);
  }
  agent_store_f(arr + p, delays[p]);
#pragma unroll
  for (int l = 0; l < L; ++l) agent_store_f(req + l * P + p, TPER);
  {
    const int base = p * 8;  // P*8 = 1,048,576 >= NNETS
#pragma unroll
    for (int j = 0; j < 8; ++j) {
      const int idx = base + j;
      if (idx < NNETS) mf[idx] = mask[idx] ? 1.0f : 0.0f;  // write-only: normal
    }
  }
  gbar(cnt, flag, 1);

  // ---- 31 fused steps, one grid barrier each ----
  for (int i = 1; i < L; ++i) {
    const int lf = i, lb = L - 1 - i;
    {  // forward: arr[lf][p] = max(valid fanin max, own delay)
      const float d = delays[lf * P + p];
      const int2 s = *reinterpret_cast<const int2*>(src + (size_t)(lf - 1) * P * 2 + p * 2);
      const int2 n = *reinterpret_cast<const int2*>(net + (size_t)(lf - 1) * P * 2 + p * 2);
      const float* ap = arr + (size_t)(lf - 1) * P;
      float v0 = ap[s.x] + d;  // normal cached gathers (fresh by construction)
      float v1 = ap[s.y] + d;
      if ((bits[n.x >> 5] >> (n.x & 31)) & 1) v0 = NEGV;
      if ((bits[n.y >> 5] >> (n.y & 31)) & 1) v1 = NEGV;
      agent_store_f(arr + (size_t)lf * P + p, fmaxf(fmaxf(v0, v1), d));
    }
    {  // backward: scatter-min into req[lb] from req[lb+1]
      const float rq = agent_load_f(req + (size_t)(lb + 1) * P + p);
      const float d = delays[(lb + 1) * P + p];
      const float c = rq - d;
      const int2 s = *reinterpret_cast<const int2*>(src + (size_t)lb * P * 2 + p * 2);
      const int2 n = *reinterpret_cast<const int2*>(net + (size_t)lb * P * 2 + p * 2);
      float* rp = req + (size_t)lb * P;
      if (!((bits[n.x >> 5] >> (n.x & 31)) & 1)) atomic_min_f32(rp + s.x, c);
      if (!((bits[n.y >> 5] >> (n.y & 31)) & 1)) atomic_min_f32(rp + s.y, c);
    }
    gbar(cnt, flag, i + 1);
  }

  // ---- epilogue: slack = required - arrival ----
  for (int l = 0; l < L; ++l) {
    const float a = arr[(size_t)l * P + p];              // normal (fresh-only)
    const float r = agent_load_f(req + (size_t)l * P + p);  // atomics -> agent
    slk[(size_t)l * P + p] = r - a;
  }
}

// ---- proven R4 fallback path (used only if cooperative launch fails) ----
__global__ __launch_bounds__(256) void sta_init(
    const float* __restrict__ delays, const int* __restrict__ mask,
    float* __restrict__ out) {
  int i4 = (blockIdx.x * blockDim.x + threadIdx.x) * 4;
  if (i4 < LP) {
    float4 ten = {TPER, TPER, TPER, TPER};
    *reinterpret_cast<float4*>(out + LP + i4) = ten;
    if (i4 < P)
      *reinterpret_cast<float4*>(out + i4) =
          *reinterpret_cast<const float4*>(delays + i4);
  }
  if (i4 < NNETS) {
    int4 m = *reinterpret_cast<const int4*>(mask + i4);
    float4 f = {(float)(m.x != 0), (float)(m.y != 0), (float)(m.z != 0),
                (float)(m.w != 0)};
    *reinterpret_cast<float4*>(out + 3 * LP + i4) = f;
  }
}

__global__ __launch_bounds__(256) void sta_step_direct(
    const float* __restrict__ delays, const int* __restrict__ src,
    const int* __restrict__ net, const int* __restrict__ mask,
    float* __restrict__ out, int i) {
  const int p = blockIdx.x * blockDim.x + threadIdx.x;
  float* arr = out;
  float* req = out + LP;
  const int lf = i, lb = L - 1 - i;
  {
    const float d = delays[lf * P + p];
    const int2 s = *reinterpret_cast<const int2*>(src + (size_t)(lf - 1) * P * 2 + p * 2);
    const int2 n = *reinterpret_cast<const int2*>(net + (size_t)(lf - 1) * P * 2 + p * 2);
    const float* ap = arr + (lf - 1) * P;
    const float v0 = mask[n.x] ? NEGV : ap[s.x] + d;
    const float v1 = mask[n.y] ? NEGV : ap[s.y] + d;
    arr[lf * P + p] = fmaxf(fmaxf(v0, v1), d);
  }
  {
    const float c = req[(lb + 1) * P + p] - delays[(lb + 1) * P + p];
    const int2 s = *reinterpret_cast<const int2*>(src + (size_t)lb * P * 2 + p * 2);
    const int2 n = *reinterpret_cast<const int2*>(net + (size_t)lb * P * 2 + p * 2);
    float* rp = req + lb * P;
    if (!mask[n.x]) atomic_min_f32(rp + s.x, c);
    if (!mask[n.y]) atomic_min_f32(rp + s.y, c);
  }
}

__global__ __launch_bounds__(256) void sta_slack(float* __restrict__ out) {
  int i4 = (blockIdx.x * blockDim.x + threadIdx.x) * 4;
  if (i4 < LP) {
    float4 a = *reinterpret_cast<const float4*>(out + i4);
    float4 r = *reinterpret_cast<const float4*>(out + LP + i4);
    float4 s = {r.x - a.x, r.y - a.y, r.z - a.z, r.w - a.w};
    *reinterpret_cast<float4*>(out + 2 * LP + i4) = s;
  }
}

extern "C" void kernel_launch(void* const* d_in, const int* in_sizes, int n_in,
                              void* d_out, int out_size, void* d_ws, size_t ws_size,
                              hipStream_t stream) {
  const float* delays = (const float*)d_in[0];
  const int* src = (const int*)d_in[1];
  const int* net = (const int*)d_in[2];
  const int* mask = (const int*)d_in[3];  // JAX bool delivered as int32
  float* out = (float*)d_out;
  int* ws = (int*)d_ws;

  if (ws_size >= (size_t)(WS_FLAG + 32) * sizeof(int)) {
    // zero barrier cnt+flag (ws is poisoned 0xAA before every call)
    hipMemsetAsync((char*)d_ws + (size_t)WS_CNT * sizeof(int), 0, 256, stream);
    void* args[] = {(void*)&delays, (void*)&src, (void*)&net,
                    (void*)&mask, (void*)&out, (void*)&ws};
    hipError_t e = hipLaunchCooperativeKernel((const void*)sta_persist,
                                              dim3(NBLK), dim3(TPB), args, 0,
                                              stream);
    if (e == hipSuccess) return;
    (void)hipGetLastError();  // clear; fall through to proven path
  }
  sta_init<<<LP / 1024, 256, 0, stream>>>(delays, mask, out);
  for (int i = 1; i < L; ++i)
    sta_step_direct<<<P / 256, 256, 0, stream>>>(delays, src, net, mask, out, i);
  sta_slack<<<LP / 1024, 256, 0, stream>>>(out);
}

// Round 6
// 631.197 us; speedup vs baseline: 1.1430x; 1.1430x over previous
//
#include <hip/hip_runtime.h>

// Levelized STA, persistent cooperative kernel, ARC-parallel (4P threads).
// R5 post-mortem: per-step floor is random-request latency x insufficient
// occupancy (512 blocks = 8 waves/CU, Occ 24%). R6: 2048 blocks = 32 waves/CU.
//
// d_out (floats): [0,LP) arrival | [LP,2LP) required | [2LP,3LP) slack
//                 | [3LP,3LP+NNETS) mask as 0.0/1.0
// d_ws (ints): [0,32768) net-ignore bitmask | [32768,33792) 64 group counters
//              (stride 16) | [33808] cnt2 | [33840] flag
//
// XCD-coherence recipe (proven exact in R5, absmax 0.0):
//  - cross-block-visible writes (arr, req init, bits): agent-scope stores
//    (write-through past the non-coherent per-XCD L2s)
//  - reads of atomic-updated req: agent-scope loads
//  - arr gathers / bits reads: normal cached loads — safe because every kernel
//    launch begins with L2 invalidate (dirty poison written back pre-launch)
//    and each datum is written before any XCD first reads it; caching the
//    gather region in L2 is the point.
constexpr int L = 32;
constexpr int P = 131072;        // 2^17
constexpr int LP = L * P;
constexpr int NNETS = 1000000;
constexpr int NBLK = 2048;
constexpr int TPB = 256;
constexpr int NTHR = NBLK * TPB;  // 524288 = 4P
constexpr float TPER = 10.0f;
constexpr float NEGV = -1e30f;
// ws layout (int offsets)
constexpr int WS_BITS = 0;        // 32768 words (1,048,576 bits >= NNETS)
constexpr int WS_CNT1 = 32768;    // 64 counters, stride 16 ints (64B lines)
constexpr int WS_CNT2 = 33808;
constexpr int WS_FLAG = 33840;
constexpr int WS_ZERO_BEG = 32768;
constexpr int WS_ZERO_END = 33856;

__device__ __forceinline__ float agent_load_f(const float* p) {
  return __hip_atomic_load(p, __ATOMIC_RELAXED, __HIP_MEMORY_SCOPE_AGENT);
}
__device__ __forceinline__ void agent_store_f(float* p, float v) {
  __hip_atomic_store(p, v, __ATOMIC_RELAXED, __HIP_MEMORY_SCOPE_AGENT);
}

// Float atomic-min via int-min (>=0) / uint-max (<0); exact for all sign mixes.
__device__ __forceinline__ void atomic_min_f32(float* addr, float val) {
  if (val >= 0.0f) {
    atomicMin(reinterpret_cast<int*>(addr), __float_as_int(val));
  } else {
    atomicMax(reinterpret_cast<unsigned int*>(addr), __float_as_uint(val));
  }
}

// Two-level grid barrier: monotonic epoch, no counter reset. 64 groups of 32
// blocks; arrival contention is 32-deep per line instead of 2048-deep.
__device__ __forceinline__ void gbar(int* ws, int epoch) {
  asm volatile("s_waitcnt vmcnt(0)" ::: "memory");  // drain stores + atomics
  __syncthreads();
  if (threadIdx.x == 0) {
    int* flag = ws + WS_FLAG;
    int* cnt1 = ws + WS_CNT1 + ((blockIdx.x >> 5) << 4);
    int o1 = __hip_atomic_fetch_add(cnt1, 1, __ATOMIC_RELAXED,
                                    __HIP_MEMORY_SCOPE_AGENT);
    if (o1 == epoch * 32 - 1) {  // last block of this group this epoch
      int o2 = __hip_atomic_fetch_add(ws + WS_CNT2, 1, __ATOMIC_RELAXED,
                                      __HIP_MEMORY_SCOPE_AGENT);
      if (o2 == epoch * 64 - 1)  // last group
        __hip_atomic_store(flag, epoch, __ATOMIC_RELAXED,
                           __HIP_MEMORY_SCOPE_AGENT);
    }
    while (__hip_atomic_load(flag, __ATOMIC_RELAXED,
                             __HIP_MEMORY_SCOPE_AGENT) < epoch) {
      __builtin_amdgcn_s_sleep(2);
    }
  }
  __syncthreads();
}

__global__ __launch_bounds__(TPB, 8) void sta_persist(
    const float* __restrict__ delays, const int* __restrict__ src,
    const int* __restrict__ net, const int* __restrict__ mask,
    float* __restrict__ out, int* __restrict__ ws) {
  const int t = blockIdx.x * TPB + threadIdx.x;  // [0, 4P)
  const int lane = threadIdx.x & 63;
  float* arr = out;
  float* req = out + LP;
  float* slk = out + 2 * LP;
  float* mf = out + 3 * LP;
  int* bits = ws + WS_BITS;

  // ---- prologue (fully parallel) ----
  // net-ignore bit-vector via wave ballot: wave covers 64 consecutive nets.
#pragma unroll
  for (int j = 0; j < 2; ++j) {
    const int idx = j * NTHR + t;
    int mv = 0;
    if (idx < NNETS) mv = mask[idx];
    unsigned long long bal = __ballot(mv != 0);
    if (lane == 0) {
      const int word = (j * NTHR + (t & ~63)) >> 5;  // even, 8B-aligned
      __hip_atomic_store(reinterpret_cast<unsigned long long*>(bits + word),
                         bal, __ATOMIC_RELAXED, __HIP_MEMORY_SCOPE_AGENT);
    }
  }
  // mask -> float 0/1 output tail (2 nets/thread; NNETS even so pairs align)
  {
    const int idx = t * 2;
    if (idx < NNETS) {
      const int2 m = *reinterpret_cast<const int2*>(mask + idx);
      float2 f = {m.x ? 1.0f : 0.0f, m.y ? 1.0f : 0.0f};
      *reinterpret_cast<float2*>(mf + idx) = f;  // write-only region: normal
    }
  }
  // arrival level 0 = delays level 0
  if (t < P) agent_store_f(arr + t, delays[t]);
  // required = TPER everywhere (8 coalesced chunks; 8*NTHR == LP)
#pragma unroll
  for (int c = 0; c < 8; ++c) agent_store_f(req + c * NTHR + t, TPER);
  gbar(ws, 1);

  // ---- 31 fused steps, arc-parallel ----
  const int half = t >> 18;          // 0: forward, 1: backward (2P = 1<<18)
  const int a = t & (2 * P - 1);     // arc id within half
  const int p = a >> 1;              // pin; arc k = a&1 == lane&1

  for (int i = 1; i < L; ++i) {
    if (half == 0) {  // forward: arr[i][p] = max(valid fanin max, own delay)
      const int lf = i;
      const float d = delays[lf * P + p];
      const int s = src[(size_t)(lf - 1) * 2 * P + a];
      const int n = net[(size_t)(lf - 1) * 2 * P + a];
      float v = arr[(size_t)(lf - 1) * P + s] + d;  // normal cached gather
      if ((bits[n >> 5] >> (n & 31)) & 1) v = NEGV;
      const float vo = __shfl_xor(v, 1);            // partner arc's value
      if ((a & 1) == 0)
        agent_store_f(arr + (size_t)lf * P + p, fmaxf(fmaxf(v, vo), d));
    } else {          // backward: scatter-min into req[lb] from req[lb+1]
      const int lb = L - 1 - i;
      float c0 = 0.0f;
      if ((a & 1) == 0)
        c0 = agent_load_f(req + (size_t)(lb + 1) * P + p) -
             delays[(lb + 1) * P + p];
      const float c = __shfl(c0, lane & 62);         // share within pin pair
      const int s = src[(size_t)lb * 2 * P + a];
      const int n = net[(size_t)lb * 2 * P + a];
      if (!((bits[n >> 5] >> (n & 31)) & 1))
        atomic_min_f32(req + (size_t)lb * P + s, c);
    }
    gbar(ws, i + 1);
  }

  // ---- epilogue: slack = required - arrival ----
#pragma unroll
  for (int c = 0; c < 8; ++c) {
    const int idx = c * NTHR + t;
    const float av = arr[idx];                 // fresh-only: normal
    const float rv = agent_load_f(req + idx);  // atomic-updated: agent
    slk[idx] = rv - av;
  }
}

// ---- proven fallback chain (R2 path, 616us) if cooperative launch fails ----
__global__ __launch_bounds__(256) void sta_init(
    const float* __restrict__ delays, const int* __restrict__ mask,
    float* __restrict__ out) {
  int i4 = (blockIdx.x * blockDim.x + threadIdx.x) * 4;
  if (i4 < LP) {
    float4 ten = {TPER, TPER, TPER, TPER};
    *reinterpret_cast<float4*>(out + LP + i4) = ten;
    if (i4 < P)
      *reinterpret_cast<float4*>(out + i4) =
          *reinterpret_cast<const float4*>(delays + i4);
  }
  if (i4 < NNETS) {
    int4 m = *reinterpret_cast<const int4*>(mask + i4);
    float4 f = {(float)(m.x != 0), (float)(m.y != 0), (float)(m.z != 0),
                (float)(m.w != 0)};
    *reinterpret_cast<float4*>(out + 3 * LP + i4) = f;
  }
}

__global__ __launch_bounds__(256) void sta_step_direct(
    const float* __restrict__ delays, const int* __restrict__ src,
    const int* __restrict__ net, const int* __restrict__ mask,
    float* __restrict__ out, int i) {
  const int p = blockIdx.x * blockDim.x + threadIdx.x;
  float* arr = out;
  float* req = out + LP;
  const int lf = i, lb = L - 1 - i;
  {
    const float d = delays[lf * P + p];
    const int2 s = *reinterpret_cast<const int2*>(src + (size_t)(lf - 1) * P * 2 + p * 2);
    const int2 n = *reinterpret_cast<const int2*>(net + (size_t)(lf - 1) * P * 2 + p * 2);
    const float* ap = arr + (lf - 1) * P;
    const float v0 = mask[n.x] ? NEGV : ap[s.x] + d;
    const float v1 = mask[n.y] ? NEGV : ap[s.y] + d;
    arr[lf * P + p] = fmaxf(fmaxf(v0, v1), d);
  }
  {
    const float c = req[(lb + 1) * P + p] - delays[(lb + 1) * P + p];
    const int2 s = *reinterpret_cast<const int2*>(src + (size_t)lb * P * 2 + p * 2);
    const int2 n = *reinterpret_cast<const int2*>(net + (size_t)lb * P * 2 + p * 2);
    float* rp = req + lb * P;
    if (!mask[n.x]) atomic_min_f32(rp + s.x, c);
    if (!mask[n.y]) atomic_min_f32(rp + s.y, c);
  }
}

__global__ __launch_bounds__(256) void sta_slack(float* __restrict__ out) {
  int i4 = (blockIdx.x * blockDim.x + threadIdx.x) * 4;
  if (i4 < LP) {
    float4 a = *reinterpret_cast<const float4*>(out + i4);
    float4 r = *reinterpret_cast<const float4*>(out + LP + i4);
    float4 s = {r.x - a.x, r.y - a.y, r.z - a.z, r.w - a.w};
    *reinterpret_cast<float4*>(out + 2 * LP + i4) = s;
  }
}

extern "C" void kernel_launch(void* const* d_in, const int* in_sizes, int n_in,
                              void* d_out, int out_size, void* d_ws, size_t ws_size,
                              hipStream_t stream) {
  const float* delays = (const float*)d_in[0];
  const int* src = (const int*)d_in[1];
  const int* net = (const int*)d_in[2];
  const int* mask = (const int*)d_in[3];  // JAX bool delivered as int32
  float* out = (float*)d_out;
  int* ws = (int*)d_ws;

  if (ws_size >= (size_t)WS_ZERO_END * sizeof(int)) {
    // zero barrier counters + flag (ws poisoned 0xAA before every call)
    hipMemsetAsync((char*)d_ws + (size_t)WS_ZERO_BEG * sizeof(int), 0,
                   (size_t)(WS_ZERO_END - WS_ZERO_BEG) * sizeof(int), stream);
    void* args[] = {(void*)&delays, (void*)&src, (void*)&net,
                    (void*)&mask, (void*)&out, (void*)&ws};
    hipError_t e = hipLaunchCooperativeKernel((const void*)sta_persist,
                                              dim3(NBLK), dim3(TPB), args, 0,
                                              stream);
    if (e == hipSuccess) return;
    (void)hipGetLastError();  // clear; fall through to proven path
  }
  sta_init<<<LP / 1024, 256, 0, stream>>>(delays, mask, out);
  for (int i = 1; i < L; ++i)
    sta_step_direct<<<P / 256, 256, 0, stream>>>(delays, src, net, mask, out, i);
  sta_slack<<<LP / 1024, 256, 0, stream>>>(out);
}